// Round 15
// baseline (1099.541 us; speedup 1.0000x reference)
//
#include <hip/hip_runtime.h>
#include <stdint.h>

#define N_NODES 8192
#define N_EDGES 65536
#define N_TRIPLES (N_EDGES + N_NODES)   // 73728
#define D 768
#define D2 1536
#define NREL 38
#define BATCH 8
#define SENTN 512                        // B*S
#define OUT1_OFF ((size_t)N_TRIPLES * D)                     // 56623104
#define OUT2_OFF (OUT1_OFF + (size_t)BATCH * N_TRIPLES)      // 57212928

// ===== PROBE ROUND 2: rep counts lift each kernel above the ~172us fill bar so
// rocprof top-5 shows OUR kernels with counters. GEMM uses accumulate-32x +
// exact 2^-5 scale => bit-identical output, DCE-impossible. absmax tripwire:
// must stay exactly 0.005615234.
#define PREP_REP 24
#define GEMM_REP 32
#define OUT_REP 4

typedef __attribute__((ext_vector_type(4))) float f32x4;
typedef __attribute__((ext_vector_type(2))) float f32x2;
typedef __attribute__((ext_vector_type(4))) unsigned short ushort4v;

static __device__ __forceinline__ unsigned short f2bf(float f) {
  unsigned u = __builtin_bit_cast(unsigned, f);
  u += 0x7FFFu + ((u >> 16) & 1u);
  return (unsigned short)(u >> 16);
}

// ================= merged prep (R14 bodies; rep loop) =================
__global__ void k_prep(const int* __restrict__ cids, const float* __restrict__ cemb,
                       unsigned char* __restrict__ x8,
                       const float* __restrict__ W, unsigned char* __restrict__ wt8,
                       const float* __restrict__ relemb, const float* __restrict__ selfemb,
                       float* __restrict__ partials,
                       const int* __restrict__ sent, unsigned int* __restrict__ nmask) {
  __shared__ __align__(16) char smraw[32 * 33 * 4];
#pragma unroll 1
  for (int rep = 0; rep < PREP_REP; ++rep) {
    asm volatile("" ::: "memory");
    for (int b = blockIdx.x; b < 7562; b += 2048) {
      __syncthreads();   // smraw reuse guard
      if (b < 6144) {
        int t4 = b * 256 + threadIdx.x;
        int row = t4 / (D / 4);
        int c4 = t4 % (D / 4);
        int cid = cids[row];
        float4 v = ((const float4*)(cemb + (size_t)cid * D))[c4];
        int p = __builtin_amdgcn_cvt_pk_fp8_f32(v.x, v.y, 0, false);
        p = __builtin_amdgcn_cvt_pk_fp8_f32(v.z, v.w, p, true);
        *(int*)(x8 + (size_t)t4 * 4) = p;
      } else if (b < 7296) {
        float (*tile)[33] = (float(*)[33])smraw;
        int idx = b - 6144;
        int kb = (idx % 24) * 32;
        int jb = (idx / 24) * 32;
        int tx = threadIdx.x % 32;
        int ty = threadIdx.x / 32;
#pragma unroll
        for (int i = 0; i < 4; ++i) {
          int k = kb + ty + i * 8;
          int j = jb + tx;
          float v = (j < D) ? W[(size_t)k * D + j] : W[(size_t)(2 * D + k) * D + (j - D)];
          tile[ty + i * 8][tx] = v;
        }
        __syncthreads();
#pragma unroll
        for (int i = 0; i < 4; ++i) {
          int j = jb + ty + i * 8;
          int k = kb + tx;
          float v = tile[tx][ty + i * 8];
          wt8[(size_t)j * D + k] =
              (unsigned char)(__builtin_amdgcn_cvt_pk_fp8_f32(v, v, 0, false) & 0xFF);
        }
      } else if (b < 7530) {
        int idx = b - 7296;        // 0..233
        int r = idx / 6;           // 0..38
        int ch = idx % 6;          // K-chunk of 128
        const float* src = (r < NREL) ? (relemb + (size_t)r * D) : selfemb;
        int c = threadIdx.x;
        const float* W2 = W + (size_t)D * D;
        float a0 = 0.f, a1 = 0.f, a2 = 0.f;
        int k0 = ch * 128;
        for (int k = 0; k < 128; ++k) {
          float s = src[k0 + k];
          const float* wr = W2 + (size_t)(k0 + k) * D;
          a0 += s * wr[c];
          a1 += s * wr[c + 256];
          a2 += s * wr[c + 512];
        }
        float* p = partials + (size_t)idx * D;
        p[c] = a0;
        p[c + 256] = a1;
        p[c + 512] = a2;
      } else {
        int* ls = (int*)smraw;
        for (int i = threadIdx.x; i < SENTN; i += 256) ls[i] = sent[i];
        __syncthreads();
        int n = (b - 7530) * 256 + threadIdx.x;
        int cid = cids[n];
        unsigned m = 0;
#pragma unroll 16
        for (int s = 0; s < SENTN; ++s)
          m |= (ls[s] == cid) ? (1u << (s >> 6)) : 0u;
        nmask[n] = m;
      }
    }
  }
}

// ================= fp8 GEMM (R14 structure; 32x-accumulate probe) =================
__global__ void k_gemm(const unsigned char* __restrict__ A,
                       const unsigned char* __restrict__ BT,
                       unsigned char* __restrict__ xw8,
                       const float* __restrict__ partials, float* __restrict__ relw2,
                       const float* __restrict__ bias,
                       const int* __restrict__ cids, const int* __restrict__ eidx,
                       const float* __restrict__ eattr, const unsigned* __restrict__ nmask,
                       float* __restrict__ out) {
  __shared__ __align__(16) unsigned char lsA[2][256 * 64];   // 32KB
  __shared__ __align__(16) unsigned char lsB[2][128 * 64];   // 16KB
  const int bid = blockIdx.x;
  const int tid = threadIdx.x;

  if (bid >= 384) {
#pragma unroll 1
    for (int rep = 0; rep < GEMM_REP; ++rep) {
      asm volatile("" ::: "memory");
      if (bid < 423) {
        int r = bid - 384;
        const float* p = partials + (size_t)r * 6 * D;
#pragma unroll
        for (int j = 0; j < 2; ++j) {
          int cc = tid + j * 512;
          if (cc < D) {
            float s = 0.f;
#pragma unroll
            for (int ch = 0; ch < 6; ++ch) s += p[(size_t)ch * D + cc];
            relw2[(size_t)r * D + cc] = s;
          }
        }
      } else {
        int t = (bid - 423) * 512 + tid;   // 144*512 = 73728 exact
        int h, tl;
        float rel;
        if (t < N_EDGES) {
          h = eidx[t];
          tl = eidx[N_EDGES + t];
          rel = (float)(int)eattr[2 * t];
        } else {
          h = t - N_EDGES;
          tl = h;
          rel = (float)NREL;
        }
        float* o2 = out + OUT2_OFF + (size_t)t * 3;
        __builtin_nontemporal_store((float)cids[h], o2 + 0);
        __builtin_nontemporal_store(rel, o2 + 1);
        __builtin_nontemporal_store((float)cids[tl], o2 + 2);
        unsigned m = nmask[h] | nmask[tl];
        float* o1 = out + OUT1_OFF;
#pragma unroll
        for (int bb = 0; bb < BATCH; ++bb)
          __builtin_nontemporal_store(((m >> bb) & 1u) ? 1.0f : 0.0f,
                                      o1 + (size_t)bb * N_TRIPLES + t);
      }
    }
    return;
  }

  const int lane = tid & 63;
  const int wid = tid >> 6;           // 0..7
  const int wr = wid >> 1;            // 0..3 -> 64-row band of 256
  const int wc = wid & 1;             // 0..1 -> 64-col band of 128

  const int swz = (bid & 7) * 48 + (bid >> 3);
  const int arow0 = (swz / 12) * 256;
  const int bcol0 = (swz % 12) * 128;

  f32x4 acc[4][4] = {};

  const int gpair = (tid & 3) ^ ((tid >> 3) & 3);
  const unsigned char* ga = A + (size_t)(arow0 + (tid >> 2)) * D + gpair * 16;
  const unsigned char* gb = BT + (size_t)(bcol0 + (tid >> 2)) * D + gpair * 16;

  const int lr = lane & 15;
  const int hi = lane >> 4;
  const int fsw = (lr >> 1) & 3;

#define STAGE(BUF, K0)                                                                 \
  {                                                                                    \
    _Pragma("unroll") for (int c = 0; c < 2; ++c)                                      \
      __builtin_amdgcn_global_load_lds(                                                \
          (const __attribute__((address_space(1))) void*)(ga + (size_t)c * 128 * D + (K0)), \
          (__attribute__((address_space(3))) void*)(&lsA[BUF][c * 8192 + tid * 16]),   \
          16, 0, 0);                                                                   \
    __builtin_amdgcn_global_load_lds(                                                  \
        (const __attribute__((address_space(1))) void*)(gb + (K0)),                    \
        (__attribute__((address_space(3))) void*)(&lsB[BUF][tid * 16]), 16, 0, 0);     \
  }

#define COMPUTE(BUF)                                                                   \
  {                                                                                    \
    const unsigned char* sA = lsA[BUF];                                                \
    const unsigned char* sB = lsB[BUF];                                                \
    _Pragma("unroll") for (int kk = 0; kk < 2; ++kk) {                                 \
      const int pair = kk * 2 + (hi >> 1);                                             \
      const int boff = ((pair ^ fsw) * 16) + (hi & 1) * 8;                             \
      long af[4], bfv[4];                                                              \
      _Pragma("unroll") for (int m = 0; m < 4; ++m)                                    \
          af[m] = *(const long*)(sA + (wr * 64 + m * 16 + lr) * 64 + boff);            \
      _Pragma("unroll") for (int n = 0; n < 4; ++n)                                    \
          bfv[n] = *(const long*)(sB + (wc * 64 + n * 16 + lr) * 64 + boff);           \
      _Pragma("unroll") for (int m = 0; m < 4; ++m)                                    \
          _Pragma("unroll") for (int n = 0; n < 4; ++n)                                \
              acc[m][n] = __builtin_amdgcn_mfma_f32_16x16x32_fp8_fp8(af[m], bfv[n],    \
                                                                     acc[m][n], 0, 0, 0); \
    }                                                                                  \
  }

  // 32 reps accumulate 32x the K-sum; epilogue scales by 2^-5 (exact).
#pragma unroll 1
  for (int rep = 0; rep < GEMM_REP; ++rep) {
    STAGE(0, 0)
    STAGE(1, 64)
#pragma unroll
    for (int t = 0; t < 12; ++t) {
      if (t < 11) { asm volatile("s_waitcnt vmcnt(3)" ::: "memory"); }
      else        { asm volatile("s_waitcnt vmcnt(0)" ::: "memory"); }
      __builtin_amdgcn_s_barrier();
      if (t & 1) COMPUTE(1) else COMPUTE(0)
      asm volatile("" ::: "memory");
      __builtin_amdgcn_s_barrier();
      if (t + 2 < 12) { if (t & 1) STAGE(1, (t + 2) * 64) else STAGE(0, (t + 2) * 64) }
    }
  }
#undef STAGE
#undef COMPUTE

  const int crow = hi * 4;
  const bool addb = (bcol0 < D);
  const float sc = 1.0f / GEMM_REP;     // 2^-5: exponent-only, mantissa-exact
#pragma unroll
  for (int m = 0; m < 4; ++m) {
    int row = arow0 + wr * 64 + m * 16 + crow;
#pragma unroll
    for (int n = 0; n < 4; ++n) {
      int col = bcol0 + wc * 64 + n * 16 + lr;
      float bv = addb ? bias[col] : 0.f;
      unsigned char* cp = xw8 + (size_t)row * D2 + col;
      int p01 = __builtin_amdgcn_cvt_pk_fp8_f32(acc[m][n][0] * sc + bv,
                                                acc[m][n][1] * sc + bv, 0, false);
      int p23 = __builtin_amdgcn_cvt_pk_fp8_f32(acc[m][n][2] * sc + bv,
                                                acc[m][n][3] * sc + bv, 0, false);
      cp[0] = (unsigned char)(p01 & 0xFF);
      cp[(size_t)1 * D2] = (unsigned char)((p01 >> 8) & 0xFF);
      cp[(size_t)2 * D2] = (unsigned char)(p23 & 0xFF);
      cp[(size_t)3 * D2] = (unsigned char)((p23 >> 8) & 0xFF);
    }
  }
}

// ================= encoded output (R12-exact; rep loop) =================
__global__ void k_out(const int* __restrict__ eidx, const float* __restrict__ eattr,
                      const unsigned char* __restrict__ xw8, const float* __restrict__ relw2,
                      float* __restrict__ out) {
  const int wid = threadIdx.x >> 6;
  const int lane = threadIdx.x & 63;
  const int t0 = blockIdx.x * 16 + wid * 4;

#pragma unroll 1
  for (int rep = 0; rep < OUT_REP; ++rep) {
    asm volatile("" ::: "memory");
    const unsigned* r1[4];
    const unsigned* r3[4];
    const f32x4* rw[4];
    float w[4];
#pragma unroll
    for (int q = 0; q < 4; ++q) {
      int t = t0 + q;
      if (t < N_EDGES) {
        int h = eidx[t];
        int tl = eidx[N_EDGES + t];
        int rel = (int)eattr[2 * t];
        w[q] = eattr[2 * t + 1];
        r1[q] = (const unsigned*)(xw8 + (size_t)h * D2);
        r3[q] = (const unsigned*)(xw8 + (size_t)tl * D2 + D);
        rw[q] = (const f32x4*)(relw2 + (size_t)rel * D);
      } else {
        int i = t - N_EDGES;
        w[q] = 1.f;
        r1[q] = (const unsigned*)(xw8 + (size_t)i * D2);
        r3[q] = (const unsigned*)(xw8 + (size_t)i * D2 + D);
        rw[q] = (const f32x4*)(relw2 + (size_t)NREL * D);
      }
    }

#pragma unroll
    for (int j = 0; j < 3; ++j) {
      const int c4 = j * 64 + lane;
      unsigned ua[4], ux[4];
      f32x4 c[4];
#pragma unroll
      for (int q = 0; q < 4; ++q) {
        ua[q] = r1[q][c4];
        ux[q] = r3[q][c4];
        c[q] = rw[q][c4];
      }
#pragma unroll
      for (int q = 0; q < 4; ++q) {
        f32x2 alo = __builtin_amdgcn_cvt_pk_f32_fp8(ua[q], false);
        f32x2 ahi = __builtin_amdgcn_cvt_pk_f32_fp8(ua[q], true);
        f32x2 xlo = __builtin_amdgcn_cvt_pk_f32_fp8(ux[q], false);
        f32x2 xhi = __builtin_amdgcn_cvt_pk_f32_fp8(ux[q], true);
        f32x4 res;
        res.x = alo[0] + w[q] * c[q].x + xlo[0];
        res.y = alo[1] + w[q] * c[q].y + xlo[1];
        res.z = ahi[0] + w[q] * c[q].z + xhi[0];
        res.w = ahi[1] + w[q] * c[q].w + xhi[1];
        f32x4* o = (f32x4*)(out + (size_t)(t0 + q) * D);
        __builtin_nontemporal_store(res, &o[c4]);
      }
    }
  }
}

extern "C" void kernel_launch(void* const* d_in, const int* in_sizes, int n_in,
                              void* d_out, int out_size, void* d_ws, size_t ws_size,
                              hipStream_t stream) {
  const int* cids = (const int*)d_in[0];
  const int* eidx = (const int*)d_in[1];
  const float* eattr = (const float*)d_in[2];
  const int* sent = (const int*)d_in[3];
  const float* cemb = (const float*)d_in[4];
  const float* relemb = (const float*)d_in[5];
  const float* selfemb = (const float*)d_in[6];
  const float* W = (const float*)d_in[7];
  const float* bias = (const float*)d_in[8];

  char* ws = (char*)d_ws;
  unsigned char* x8 = (unsigned char*)ws;                        //  6,291,456 B
  unsigned char* wt8 = (unsigned char*)(ws + 6291456);           //  1,179,648 B
  unsigned char* xw8 = (unsigned char*)(ws + 6291456 + 1179648); // 12,582,912 B
  float* relw2 = (float*)(ws + 20054016);                        //    119,808 B
  unsigned* nmask = (unsigned*)(ws + 20054016 + 119808);         //     32,768 B
  float* partials = (float*)(ws + 20054016 + 119808 + 32768);    //    718,848 B

  float* out = (float*)d_out;

  k_prep<<<dim3(2048), dim3(256), 0, stream>>>(cids, cemb, x8, W, wt8, relemb, selfemb,
                                               partials, sent, nmask);
  k_gemm<<<dim3(567), dim3(512), 0, stream>>>(x8, wt8, xw8, partials, relw2, bias,
                                              cids, eidx, eattr, nmask, out);
  k_out<<<dim3(N_TRIPLES / 16), dim3(256), 0, stream>>>(eidx, eattr, xw8, relw2, out);
}

// Round 16
// 92.871 us; speedup vs baseline: 11.8394x; 11.8394x over previous
//
#include <hip/hip_runtime.h>
#include <stdint.h>

#define N_NODES 8192
#define N_EDGES 65536
#define N_TRIPLES (N_EDGES + N_NODES)   // 73728
#define D 768
#define D2 1536
#define NREL 38
#define BATCH 8
#define SENTN 512                        // B*S
#define OUT1_OFF ((size_t)N_TRIPLES * D)                     // 56623104
#define OUT2_OFF (OUT1_OFF + (size_t)BATCH * N_TRIPLES)      // 57212928

typedef __attribute__((ext_vector_type(4))) float f32x4;
typedef __attribute__((ext_vector_type(2))) float f32x2;
typedef __attribute__((ext_vector_type(2))) long longx2;

// K-group byte interleave: within each 64B group, new_j = (j&7) | ((j>>3)&3)<<4 | ((j>>5)&1)<<3.
// Makes lane hi's kk=0/kk=1 8B chunks adjacent -> single ds_read_b128 per fragment
// (bank-identical to the verified zero-conflict bf16 pattern).
static __device__ __forceinline__ int sigma64(int j) {
  return (j & 7) | (((j >> 3) & 3) << 4) | (((j >> 5) & 1) << 3);
}

// ================= merged prep (R14 structure; interleaved x8/wt8 writes) =================
__global__ void k_prep(const int* __restrict__ cids, const float* __restrict__ cemb,
                       unsigned char* __restrict__ x8,
                       const float* __restrict__ W, unsigned char* __restrict__ wt8,
                       const float* __restrict__ relemb, const float* __restrict__ selfemb,
                       float* __restrict__ partials,
                       const int* __restrict__ sent, unsigned int* __restrict__ nmask) {
  __shared__ __align__(16) char smraw[32 * 33 * 4];
  for (int b = blockIdx.x; b < 7562; b += 2048) {
    __syncthreads();   // smraw reuse guard between virtual blocks
    if (b < 6144) {
      int t4 = b * 256 + threadIdx.x;
      int row = t4 / (D / 4);
      int c4 = t4 % (D / 4);
      int cid = cids[row];
      float4 v = ((const float4*)(cemb + (size_t)cid * D))[c4];
      int p = __builtin_amdgcn_cvt_pk_fp8_f32(v.x, v.y, 0, false);
      p = __builtin_amdgcn_cvt_pk_fp8_f32(v.z, v.w, p, true);
      int k0 = c4 * 4;
      int off = (k0 & ~63) + sigma64(k0 & 63);   // j%4==0 -> stays 4B-aligned
      *(int*)(x8 + (size_t)row * D + off) = p;
    } else if (b < 7296) {
      float (*tile)[33] = (float(*)[33])smraw;
      int idx = b - 6144;
      int kb = (idx % 24) * 32;
      int jb = (idx / 24) * 32;
      int tx = threadIdx.x % 32;
      int ty = threadIdx.x / 32;
#pragma unroll
      for (int i = 0; i < 4; ++i) {
        int k = kb + ty + i * 8;
        int j = jb + tx;
        float v = (j < D) ? W[(size_t)k * D + j] : W[(size_t)(2 * D + k) * D + (j - D)];
        tile[ty + i * 8][tx] = v;
      }
      __syncthreads();
#pragma unroll
      for (int i = 0; i < 4; ++i) {
        int j = jb + ty + i * 8;
        int k = kb + tx;
        float v = tile[tx][ty + i * 8];
        int off = (k & ~63) + sigma64(k & 63);
        wt8[(size_t)j * D + off] =
            (unsigned char)(__builtin_amdgcn_cvt_pk_fp8_f32(v, v, 0, false) & 0xFF);
      }
    } else if (b < 7530) {
      int idx = b - 7296;        // 0..233
      int r = idx / 6;           // 0..38
      int ch = idx % 6;          // K-chunk of 128
      const float* src = (r < NREL) ? (relemb + (size_t)r * D) : selfemb;
      int c = threadIdx.x;
      const float* W2 = W + (size_t)D * D;
      float a0 = 0.f, a1 = 0.f, a2 = 0.f;
      int k0 = ch * 128;
      for (int k = 0; k < 128; ++k) {
        float s = src[k0 + k];
        const float* wr = W2 + (size_t)(k0 + k) * D;
        a0 += s * wr[c];
        a1 += s * wr[c + 256];
        a2 += s * wr[c + 512];
      }
      float* p = partials + (size_t)idx * D;
      p[c] = a0;
      p[c + 256] = a1;
      p[c + 512] = a2;
    } else {
      int* ls = (int*)smraw;
      for (int i = threadIdx.x; i < SENTN; i += 256) ls[i] = sent[i];
      __syncthreads();
      int n = (b - 7530) * 256 + threadIdx.x;
      int cid = cids[n];
      unsigned m = 0;
#pragma unroll 16
      for (int s = 0; s < SENTN; ++s)
        m |= (ls[s] == cid) ? (1u << (s >> 6)) : 0u;
      nmask[n] = m;
    }
  }
}

// ================= fp8 GEMM: 256x128, 8 waves, b128 LDS reads =================
__global__ void k_gemm(const unsigned char* __restrict__ A,
                       const unsigned char* __restrict__ BT,
                       unsigned char* __restrict__ xw8,
                       const float* __restrict__ partials, float* __restrict__ relw2,
                       const float* __restrict__ bias,
                       const int* __restrict__ cids, const int* __restrict__ eidx,
                       const float* __restrict__ eattr, const unsigned* __restrict__ nmask,
                       float* __restrict__ out) {
  __shared__ __align__(16) unsigned char lsA[2][256 * 64];   // 32KB
  __shared__ __align__(16) unsigned char lsB[2][128 * 64];   // 16KB
  const int bid = blockIdx.x;
  const int tid = threadIdx.x;

  if (bid >= 384) {
    if (bid < 423) {
      int r = bid - 384;
      const float* p = partials + (size_t)r * 6 * D;
#pragma unroll
      for (int j = 0; j < 2; ++j) {
        int cc = tid + j * 512;
        if (cc < D) {
          float s = 0.f;
#pragma unroll
          for (int ch = 0; ch < 6; ++ch) s += p[(size_t)ch * D + cc];
          relw2[(size_t)r * D + cc] = s;
        }
      }
    } else {
      int t = (bid - 423) * 512 + tid;   // 144*512 = 73728 exact
      int h, tl;
      float rel;
      if (t < N_EDGES) {
        h = eidx[t];
        tl = eidx[N_EDGES + t];
        rel = (float)(int)eattr[2 * t];
      } else {
        h = t - N_EDGES;
        tl = h;
        rel = (float)NREL;
      }
      float* o2 = out + OUT2_OFF + (size_t)t * 3;
      __builtin_nontemporal_store((float)cids[h], o2 + 0);
      __builtin_nontemporal_store(rel, o2 + 1);
      __builtin_nontemporal_store((float)cids[tl], o2 + 2);
      unsigned m = nmask[h] | nmask[tl];
      float* o1 = out + OUT1_OFF;
#pragma unroll
      for (int bb = 0; bb < BATCH; ++bb)
        __builtin_nontemporal_store(((m >> bb) & 1u) ? 1.0f : 0.0f,
                                    o1 + (size_t)bb * N_TRIPLES + t);
    }
    return;
  }

  const int lane = tid & 63;
  const int wid = tid >> 6;           // 0..7
  const int wr = wid >> 1;            // 0..3 -> 64-row band of 256
  const int wc = wid & 1;             // 0..1 -> 64-col band of 128

  const int swz = (bid & 7) * 48 + (bid >> 3);
  const int arow0 = (swz / 12) * 256;
  const int bcol0 = (swz % 12) * 128;

  f32x4 acc[4][4] = {};

  // Staging: dest lane-linear; source 16B-slot pre-XOR'd with (row>>1)&3 (rule #21).
  const int gpair = (tid & 3) ^ ((tid >> 3) & 3);
  const unsigned char* ga = A + (size_t)(arow0 + (tid >> 2)) * D + gpair * 16;
  const unsigned char* gb = BT + (size_t)(bcol0 + (tid >> 2)) * D + gpair * 16;

  const int lr = lane & 15;
  const int hi = lane >> 4;
  const int fsw = (lr >> 1) & 3;
  const int rslot = (hi ^ fsw) * 16;   // b128 read slot (interleaved layout)

#define STAGE(BUF, K0)                                                                 \
  {                                                                                    \
    _Pragma("unroll") for (int c = 0; c < 2; ++c)                                      \
      __builtin_amdgcn_global_load_lds(                                                \
          (const __attribute__((address_space(1))) void*)(ga + (size_t)c * 128 * D + (K0)), \
          (__attribute__((address_space(3))) void*)(&lsA[BUF][c * 8192 + tid * 16]),   \
          16, 0, 0);                                                                   \
    __builtin_amdgcn_global_load_lds(                                                  \
        (const __attribute__((address_space(1))) void*)(gb + (K0)),                    \
        (__attribute__((address_space(3))) void*)(&lsB[BUF][tid * 16]), 16, 0, 0);     \
  }

// One b128 per fragment: low 8B = kk0, high 8B = kk1 (interleaved layout).
// MFMA order kk0-then-kk1 per K-step == previous rounds -> bit-identical acc.
#define COMPUTE(BUF)                                                                   \
  {                                                                                    \
    const unsigned char* sA = lsA[BUF];                                                \
    const unsigned char* sB = lsB[BUF];                                                \
    longx2 af[4], bfv[4];                                                              \
    _Pragma("unroll") for (int m = 0; m < 4; ++m)                                      \
        af[m] = *(const longx2*)(sA + (wr * 64 + m * 16 + lr) * 64 + rslot);           \
    _Pragma("unroll") for (int n = 0; n < 4; ++n)                                      \
        bfv[n] = *(const longx2*)(sB + (wc * 64 + n * 16 + lr) * 64 + rslot);          \
    _Pragma("unroll") for (int m = 0; m < 4; ++m)                                      \
        _Pragma("unroll") for (int n = 0; n < 4; ++n)                                  \
            acc[m][n] = __builtin_amdgcn_mfma_f32_16x16x32_fp8_fp8(af[m].x, bfv[n].x,  \
                                                                   acc[m][n], 0, 0, 0); \
    _Pragma("unroll") for (int m = 0; m < 4; ++m)                                      \
        _Pragma("unroll") for (int n = 0; n < 4; ++n)                                  \
            acc[m][n] = __builtin_amdgcn_mfma_f32_16x16x32_fp8_fp8(af[m].y, bfv[n].y,  \
                                                                   acc[m][n], 0, 0, 0); \
  }

  // 12 K-steps of 64; 3 loads/thread/STAGE -> steady in-flight 6, vmcnt(3).
  STAGE(0, 0)
  STAGE(1, 64)
#pragma unroll
  for (int t = 0; t < 12; ++t) {
    if (t < 11) { asm volatile("s_waitcnt vmcnt(3)" ::: "memory"); }
    else        { asm volatile("s_waitcnt vmcnt(0)" ::: "memory"); }
    __builtin_amdgcn_s_barrier();      // tile t ready in all waves
    if (t & 1) COMPUTE(1) else COMPUTE(0)
    asm volatile("" ::: "memory");
    __builtin_amdgcn_s_barrier();      // all waves done reading buf (t&1)
    if (t + 2 < 12) { if (t & 1) STAGE(1, (t + 2) * 64) else STAGE(0, (t + 2) * 64) }
  }
#undef STAGE
#undef COMPUTE

  // Epilogue: bias fold + fp8 pack (arithmetic unchanged).
  const int crow = hi * 4;
  const bool addb = (bcol0 < D);
#pragma unroll
  for (int m = 0; m < 4; ++m) {
    int row = arow0 + wr * 64 + m * 16 + crow;
#pragma unroll
    for (int n = 0; n < 4; ++n) {
      int col = bcol0 + wc * 64 + n * 16 + lr;
      float bv = addb ? bias[col] : 0.f;
      unsigned char* cp = xw8 + (size_t)row * D2 + col;
      int p01 = __builtin_amdgcn_cvt_pk_fp8_f32(acc[m][n][0] + bv, acc[m][n][1] + bv, 0, false);
      int p23 = __builtin_amdgcn_cvt_pk_fp8_f32(acc[m][n][2] + bv, acc[m][n][3] + bv, 0, false);
      cp[0] = (unsigned char)(p01 & 0xFF);
      cp[(size_t)1 * D2] = (unsigned char)((p01 >> 8) & 0xFF);
      cp[(size_t)2 * D2] = (unsigned char)(p23 & 0xFF);
      cp[(size_t)3 * D2] = (unsigned char)((p23 >> 8) & 0xFF);
    }
  }
}

// ================= encoded output (R12-exact) =================
__global__ void k_out(const int* __restrict__ eidx, const float* __restrict__ eattr,
                      const unsigned char* __restrict__ xw8, const float* __restrict__ relw2,
                      float* __restrict__ out) {
  const int wid = threadIdx.x >> 6;
  const int lane = threadIdx.x & 63;
  const int t0 = blockIdx.x * 16 + wid * 4;

  const unsigned* r1[4];
  const unsigned* r3[4];
  const f32x4* rw[4];
  float w[4];
#pragma unroll
  for (int q = 0; q < 4; ++q) {
    int t = t0 + q;
    if (t < N_EDGES) {
      int h = eidx[t];
      int tl = eidx[N_EDGES + t];
      int rel = (int)eattr[2 * t];
      w[q] = eattr[2 * t + 1];
      r1[q] = (const unsigned*)(xw8 + (size_t)h * D2);
      r3[q] = (const unsigned*)(xw8 + (size_t)tl * D2 + D);
      rw[q] = (const f32x4*)(relw2 + (size_t)rel * D);
    } else {
      int i = t - N_EDGES;
      w[q] = 1.f;
      r1[q] = (const unsigned*)(xw8 + (size_t)i * D2);
      r3[q] = (const unsigned*)(xw8 + (size_t)i * D2 + D);
      rw[q] = (const f32x4*)(relw2 + (size_t)NREL * D);
    }
  }

#pragma unroll
  for (int j = 0; j < 3; ++j) {
    const int c4 = j * 64 + lane;
    unsigned ua[4], ux[4];
    f32x4 c[4];
#pragma unroll
    for (int q = 0; q < 4; ++q) {
      ua[q] = r1[q][c4];
      ux[q] = r3[q][c4];
      c[q] = rw[q][c4];
    }
#pragma unroll
    for (int q = 0; q < 4; ++q) {
      f32x2 alo = __builtin_amdgcn_cvt_pk_f32_fp8(ua[q], false);
      f32x2 ahi = __builtin_amdgcn_cvt_pk_f32_fp8(ua[q], true);
      f32x2 xlo = __builtin_amdgcn_cvt_pk_f32_fp8(ux[q], false);
      f32x2 xhi = __builtin_amdgcn_cvt_pk_f32_fp8(ux[q], true);
      f32x4 res;
      res.x = alo[0] + w[q] * c[q].x + xlo[0];
      res.y = alo[1] + w[q] * c[q].y + xlo[1];
      res.z = ahi[0] + w[q] * c[q].z + xhi[0];
      res.w = ahi[1] + w[q] * c[q].w + xhi[1];
      f32x4* o = (f32x4*)(out + (size_t)(t0 + q) * D);
      __builtin_nontemporal_store(res, &o[c4]);
    }
  }
}

extern "C" void kernel_launch(void* const* d_in, const int* in_sizes, int n_in,
                              void* d_out, int out_size, void* d_ws, size_t ws_size,
                              hipStream_t stream) {
  const int* cids = (const int*)d_in[0];
  const int* eidx = (const int*)d_in[1];
  const float* eattr = (const float*)d_in[2];
  const int* sent = (const int*)d_in[3];
  const float* cemb = (const float*)d_in[4];
  const float* relemb = (const float*)d_in[5];
  const float* selfemb = (const float*)d_in[6];
  const float* W = (const float*)d_in[7];
  const float* bias = (const float*)d_in[8];

  char* ws = (char*)d_ws;
  unsigned char* x8 = (unsigned char*)ws;                        //  6,291,456 B
  unsigned char* wt8 = (unsigned char*)(ws + 6291456);           //  1,179,648 B
  unsigned char* xw8 = (unsigned char*)(ws + 6291456 + 1179648); // 12,582,912 B
  float* relw2 = (float*)(ws + 20054016);                        //    119,808 B
  unsigned* nmask = (unsigned*)(ws + 20054016 + 119808);         //     32,768 B
  float* partials = (float*)(ws + 20054016 + 119808 + 32768);    //    718,848 B

  float* out = (float*)d_out;

  k_prep<<<dim3(2048), dim3(256), 0, stream>>>(cids, cemb, x8, W, wt8, relemb, selfemb,
                                               partials, sent, nmask);
  k_gemm<<<dim3(567), dim3(512), 0, stream>>>(x8, wt8, xw8, partials, relw2, bias,
                                              cids, eidx, eattr, nmask, out);
  k_out<<<dim3(N_TRIPLES / 16), dim3(256), 0, stream>>>(eidx, eattr, xw8, relw2, out);
}